// Round 6
// baseline (748.258 us; speedup 1.0000x reference)
//
#include <hip/hip_runtime.h>
#include <hip/hip_bf16.h>
#include <cstdint>

#define DIM 32
#define OUTD 128
#define B_PART 256     // blocks in hist/partition passes
#define BSHIFT 9       // bucket = 512 nodes
#define SRCSHIFT 13    // source-sort granularity (8192 nodes per band)

// ---------------- bf16 helpers (RNE) ----------------
__device__ __forceinline__ unsigned short f32_to_bf16_rne(float f) {
    unsigned u = __float_as_uint(f);
    unsigned r = u + 0x7FFFu + ((u >> 16) & 1u);
    return (unsigned short)(r >> 16);
}
__device__ __forceinline__ float bf16_to_f32(unsigned short h) {
    return __uint_as_float(((unsigned)h) << 16);
}

// ---------------- index-load helper (int32 vs int64 inputs) ----------------
__device__ __forceinline__ int load_idx(const void* p, long long i, int is64) {
    if (is64) return (int)((const long long*)p)[i];
    return ((const int*)p)[i];
}

// Detect whether integer inputs are int64 (8B) or int32 (4B).
__global__ void detect_dtype_kernel(const void* __restrict__ edge, int* __restrict__ flag, int n_nodes) {
    __shared__ int cnt;
    if (threadIdx.x == 0) cnt = 0;
    __syncthreads();
    long long v = ((const long long*)edge)[threadIdx.x];
    int ok = (v >= 0 && v < (long long)n_nodes) ? 1 : 0;
    atomicAdd(&cnt, ok);
    __syncthreads();
    if (threadIdx.x == 0) *flag = (cnt > 128) ? 1 : 0;
}

// ---- pass 1: per-(bucket, block) histogram of destination buckets ----
__global__ __launch_bounds__(256) void hist_kernel(const void* __restrict__ edge,
                                                   const int* __restrict__ flag,
                                                   int* __restrict__ histT,
                                                   int eN, int NB, int chunk) {
    __shared__ int sh[256];
    int t = threadIdx.x, bid = blockIdx.x;
    sh[t] = 0;
    __syncthreads();
    int f = *flag;
    int s = bid * chunk, e = min(eN, s + chunk);
    for (int i = s + t; i < e; i += 256) {
        int c = load_idx(edge, (long long)eN + i, f);
        atomicAdd(&sh[c >> BSHIFT], 1);
    }
    __syncthreads();
    if (t < NB) histT[t * B_PART + bid] = sh[t];   // bucket-major layout
}

// ---- generic hierarchical exclusive scan over M ints (A: block sums) ----
__global__ __launch_bounds__(512) void scanA_kernel(const int* __restrict__ a,
                                                    int* __restrict__ sums, int M) {
    __shared__ int red[512];
    int i = blockIdx.x * 512 + threadIdx.x;
    int v = (i < M) ? a[i] : 0;
    red[threadIdx.x] = v;
    __syncthreads();
    for (int off = 256; off > 0; off >>= 1) {
        if (threadIdx.x < off) red[threadIdx.x] += red[threadIdx.x + off];
        __syncthreads();
    }
    if (threadIdx.x == 0) sums[blockIdx.x] = red[0];
}

// ---- B: exclusive scan of block sums (<=1024) ----
__global__ __launch_bounds__(1024) void scanB_kernel(int* __restrict__ sums, int nb) {
    __shared__ int part[1024];
    int t = threadIdx.x;
    int v = (t < nb) ? sums[t] : 0;
    part[t] = v;
    __syncthreads();
    for (int off = 1; off < 1024; off <<= 1) {
        int u = (t >= off) ? part[t - off] : 0;
        __syncthreads();
        part[t] += u;
        __syncthreads();
    }
    if (t < nb) sums[t] = part[t] - v;
}

// ---- C: apply (in-place exclusive scan) ----
__global__ __launch_bounds__(512) void scanC_kernel(int* __restrict__ a,
                                                    const int* __restrict__ sums, int M) {
    __shared__ int part[512];
    int t = threadIdx.x;
    int i = blockIdx.x * 512 + t;
    int v = (i < M) ? a[i] : 0;
    part[t] = v;
    __syncthreads();
    for (int off = 1; off < 512; off <<= 1) {
        int u = (t >= off) ? part[t - off] : 0;
        __syncthreads();
        part[t] += u;
        __syncthreads();
    }
    if (i < M) a[i] = part[t] - v + sums[blockIdx.x];
}

// ---- pass 2: partition edges into bucket runs; pack (r | local_c<<23) in 4B ----
__global__ __launch_bounds__(256) void partition_kernel(const void* __restrict__ edge,
                                                        const int* __restrict__ flag,
                                                        const int* __restrict__ offs,
                                                        unsigned int* __restrict__ pairs,
                                                        int eN, int NB, int chunk) {
    __shared__ int cur[256];
    int t = threadIdx.x, bid = blockIdx.x;
    if (t < NB) cur[t] = offs[t * B_PART + bid];
    __syncthreads();
    int f = *flag;
    int s = bid * chunk, e = min(eN, s + chunk);
    for (int i = s + t; i < e; i += 256) {
        int r = load_idx(edge, i, f);
        int c = load_idx(edge, (long long)eN + i, f);
        int slot = atomicAdd(&cur[c >> BSHIFT], 1);
        pairs[slot] = (unsigned)r | ((unsigned)(c & 511) << 23);
    }
}

// ---- pass 3: per-bucket CSR build; rows placed in source-band order ----
// Placement runs NP passes over the bucket's pairs, pass p placing only edges
// with src in band p (src>>SRCSHIFT == p), barrier between passes. Each row's
// list is then coarsely sorted by source, so concurrently-running conv blocks
// stream through sb in near-lockstep -> L2-resident hot window.
__global__ __launch_bounds__(256) void bucket_fill_kernel(const unsigned int* __restrict__ pairs,
                                                          const int* __restrict__ offs,
                                                          int* __restrict__ rowptr,
                                                          float* __restrict__ dinv,
                                                          int* __restrict__ csr_src,
                                                          int n, int eN, int NB, int NP) {
    __shared__ int lcnt[512];
    __shared__ int lofs[512];
    __shared__ int psum[256];
    int t = threadIdx.x, b = blockIdx.x;
    int base = b << BSHIFT;
    int nLocal = min(512, n - base);
    int s = offs[b * B_PART];
    int e = (b + 1 < NB) ? offs[(b + 1) * B_PART] : eN;
    lcnt[t] = 0;
    lcnt[t + 256] = 0;
    __syncthreads();
    for (int i = s + t; i < e; i += 256) atomicAdd(&lcnt[pairs[i] >> 23], 1);
    __syncthreads();
    int a0 = lcnt[2 * t], a1 = lcnt[2 * t + 1];
    psum[t] = a0 + a1;
    __syncthreads();
    for (int off = 1; off < 256; off <<= 1) {
        int u = (t >= off) ? psum[t - off] : 0;
        __syncthreads();
        psum[t] += u;
        __syncthreads();
    }
    int ex = psum[t] - (a0 + a1);
    lofs[2 * t] = ex;
    lofs[2 * t + 1] = ex + a0;
    __syncthreads();
    for (int j = t; j < nLocal; j += 256) {
        rowptr[base + j] = s + lofs[j];
        dinv[base + j] = rsqrtf((float)(lcnt[j] + 1));
    }
    if (b == NB - 1 && t == 0) rowptr[n] = eN;
    __syncthreads();
    lcnt[t] = lofs[t];
    lcnt[t + 256] = lofs[t + 256];
    __syncthreads();
    for (int pass = 0; pass < NP; ++pass) {
        for (int i = s + t; i < e; i += 256) {
            unsigned p = pairs[i];
            int r = (int)(p & 0x7FFFFFu);
            if ((r >> SRCSHIFT) != pass) continue;
            int lc = (int)(p >> 23);
            int slot = atomicAdd(&lcnt[lc], 1);
            csr_src[s + slot] = r;
        }
        __syncthreads();
    }
}

// prep: sb[i] = bf16(dinv[node] * x[i])
__global__ __launch_bounds__(256) void prescale_kernel(const float* __restrict__ x,
                                                       const float* __restrict__ dinv,
                                                       unsigned short* __restrict__ sb, int total) {
    int i = blockIdx.x * 256 + threadIdx.x;
    if (i >= total) return;
    sb[i] = f32_to_bf16_rne(dinv[i >> 5] * x[i]);
}

// Fused GCN conv on pre-scaled bf16 rows:
//   agg_k = dinv_c * ( sum_e sb[src_e][k] + sb[c][k] )        (sb = bf16(dinv*h))
//   o     = relu( agg @ W + b (+ res) )
//   WRITE_F32: store o to out (f32); sb_out (if non-null): bf16(dinv_c * o)
template <int HAS_RES, int WRITE_F32>
__global__ __launch_bounds__(256) void fused_conv_kernel(const unsigned short* __restrict__ sb,
                                                         const int* __restrict__ rowptr,
                                                         const int* __restrict__ src,
                                                         const float* __restrict__ dinv,
                                                         const float* __restrict__ W,
                                                         const float* __restrict__ bias,
                                                         const float* __restrict__ res,
                                                         float* __restrict__ out,
                                                         unsigned short* __restrict__ sb_out,
                                                         int n) {
    int t = threadIdx.x;
    int k = t & 31;
    float wr[32];
    #pragma unroll
    for (int j = 0; j < 32; ++j) wr[j] = W[j * 32 + k];
    float bk = bias[k];
    int g = blockIdx.x * 8 + (t >> 5);
    if (g >= n) return;
    float di = dinv[g];
    float acc = bf16_to_f32(sb[(size_t)g * 32 + k]);   // self term (pre-scaled)
    int s = rowptr[g], e = rowptr[g + 1];
    int p = s;
    for (; p + 7 < e; p += 8) {
        int sr0 = src[p];
        int sr1 = src[p + 1];
        int sr2 = src[p + 2];
        int sr3 = src[p + 3];
        int sr4 = src[p + 4];
        int sr5 = src[p + 5];
        int sr6 = src[p + 6];
        int sr7 = src[p + 7];
        float v0 = bf16_to_f32(sb[(size_t)sr0 * 32 + k]);
        float v1 = bf16_to_f32(sb[(size_t)sr1 * 32 + k]);
        float v2 = bf16_to_f32(sb[(size_t)sr2 * 32 + k]);
        float v3 = bf16_to_f32(sb[(size_t)sr3 * 32 + k]);
        float v4 = bf16_to_f32(sb[(size_t)sr4 * 32 + k]);
        float v5 = bf16_to_f32(sb[(size_t)sr5 * 32 + k]);
        float v6 = bf16_to_f32(sb[(size_t)sr6 * 32 + k]);
        float v7 = bf16_to_f32(sb[(size_t)sr7 * 32 + k]);
        acc += ((v0 + v1) + (v2 + v3)) + ((v4 + v5) + (v6 + v7));
    }
    for (; p < e; ++p) {
        int sr = src[p];
        acc += bf16_to_f32(sb[(size_t)sr * 32 + k]);
    }
    float agg = di * acc;
    float o = bk;
    #pragma unroll
    for (int j = 0; j < 32; ++j) {
        float aj = __shfl(agg, j, 32);
        o = fmaf(aj, wr[j], o);
    }
    if (HAS_RES) o += res[(size_t)g * 32 + k];
    o = fmaxf(o, 0.f);
    if (WRITE_F32) out[(size_t)g * 32 + k] = o;
    if (sb_out) sb_out[(size_t)g * 32 + k] = f32_to_bf16_rne(di * o);
}

// one block per graph: mean-pool (batch is sorted -> binary search range) + 32->128 FC
__global__ __launch_bounds__(128) void pool_fc_kernel(const float* __restrict__ h,
                                                      const void* __restrict__ batch,
                                                      const int* __restrict__ flag,
                                                      const float* __restrict__ Wl,
                                                      const float* __restrict__ bl,
                                                      float* __restrict__ out, int n) {
    __shared__ float red[4][32];
    __shared__ float sp[32];
    __shared__ int srange[2];
    int g = blockIdx.x;
    int t = threadIdx.x;
    int f = *flag;
    if (t < 2) {
        int target = g + t;
        int lo = 0, hi = n;
        while (lo < hi) {
            int mid = (lo + hi) >> 1;
            int v = load_idx(batch, mid, f);
            if (v < target) lo = mid + 1; else hi = mid;
        }
        srange[t] = lo;
    }
    __syncthreads();
    int s = srange[0], e = srange[1];
    int gi = t >> 5, k = t & 31;
    float acc = 0.f;
    for (int i = s + gi; i < e; i += 4) acc += h[(size_t)i * 32 + k];
    red[gi][k] = acc;
    __syncthreads();
    if (gi == 0) {
        float v = red[0][k] + red[1][k] + red[2][k] + red[3][k];
        sp[k] = v / fmaxf((float)(e - s), 1.0f);
    }
    __syncthreads();
    float val = bl[t];
    #pragma unroll
    for (int j = 0; j < 32; ++j) val = fmaf(sp[j], Wl[j * 128 + t], val);
    out[(size_t)g * 128 + t] = val;
}

extern "C" void kernel_launch(void* const* d_in, const int* in_sizes, int n_in,
                              void* d_out, int out_size, void* d_ws, size_t ws_size,
                              hipStream_t stream) {
    const float* x = (const float*)d_in[0];
    const void* edge = d_in[1];
    const void* batch = d_in[2];
    const float* W[6] = {(const float*)d_in[3], (const float*)d_in[5],
                         (const float*)d_in[7], (const float*)d_in[9],
                         (const float*)d_in[11], (const float*)d_in[13]};
    const float* B[6] = {(const float*)d_in[4], (const float*)d_in[6],
                         (const float*)d_in[8], (const float*)d_in[10],
                         (const float*)d_in[12], (const float*)d_in[14]};
    const float* Wl = (const float*)d_in[15];
    const float* bl = (const float*)d_in[16];
    float* out = (float*)d_out;

    int n = in_sizes[0] / DIM;      // 100000 nodes
    int eN = in_sizes[1] / 2;       // 3200000 edges
    int gN = out_size / OUTD;       // 8192 graphs

    int NB = (n + 511) >> BSHIFT;   // 196 buckets (<=256 for n<=131072)
    int M = NB * B_PART;            // hist matrix size
    int chunk = (eN + B_PART - 1) / B_PART;
    int nbA = (M + 511) / 512;
    int NP = ((n - 1) >> SRCSHIFT) + 1;   // source bands (13 for n=100k)

    char* ws = (char*)d_ws;
    size_t off = 0;
    auto alloc = [&](size_t bytes) {
        void* p = ws + off;
        off += (bytes + 255) & ~(size_t)255;
        return p;
    };
    int* flag      = (int*)alloc(4);
    int* offs      = (int*)alloc((size_t)B_PART * 256 * 4);   // hist/offsets (bucket-major)
    int* sumsA     = (int*)alloc(1024 * 4);
    int* rowptr    = (int*)alloc((size_t)(n + 1) * 4);
    float* dinv    = (float*)alloc((size_t)n * 4);
    int* csr_src   = (int*)alloc((size_t)eN * 4);
    float* bufB    = (float*)alloc((size_t)n * DIM * 4);
    unsigned short* sbX = (unsigned short*)alloc((size_t)n * DIM * 2);
    unsigned short* sbA = (unsigned short*)alloc((size_t)n * DIM * 2);
    unsigned short* sbB = (unsigned short*)alloc((size_t)n * DIM * 2);
    unsigned short* sbC = (unsigned short*)alloc((size_t)n * DIM * 2);
    size_t pairsB  = (size_t)eN * 4;
    size_t bufCB   = (size_t)n * DIM * 4;
    void* shared0  = alloc(pairsB > bufCB ? pairsB : bufCB);  // pairs, later bufC
    unsigned int* pairs = (unsigned int*)shared0;
    float* bufC    = (float*)shared0;

    detect_dtype_kernel<<<1, 256, 0, stream>>>(edge, flag, n);
    hist_kernel<<<B_PART, 256, 0, stream>>>(edge, flag, offs, eN, NB, chunk);
    scanA_kernel<<<nbA, 512, 0, stream>>>(offs, sumsA, M);
    scanB_kernel<<<1, 1024, 0, stream>>>(sumsA, nbA);
    scanC_kernel<<<nbA, 512, 0, stream>>>(offs, sumsA, M);
    partition_kernel<<<B_PART, 256, 0, stream>>>(edge, flag, offs, pairs, eN, NB, chunk);
    bucket_fill_kernel<<<NB, 256, 0, stream>>>(pairs, offs, rowptr, dinv, csr_src, n, eN, NB, NP);

    int total = n * DIM;
    prescale_kernel<<<(total + 255) / 256, 256, 0, stream>>>(x, dinv, sbX, total);

    int ab = (n + 7) / 8;

    // Res-block 1: x --(c0)--> sbA --(c1)--> bufB(+sbB)
    fused_conv_kernel<0, 0><<<ab, 256, 0, stream>>>(sbX, rowptr, csr_src, dinv, W[0], B[0], nullptr, nullptr, sbA, n);
    fused_conv_kernel<1, 1><<<ab, 256, 0, stream>>>(sbA, rowptr, csr_src, dinv, W[1], B[1], x,       bufB,    sbB, n);
    // Res-block 2: bufB --(c2)--> sbA --(c3)--> bufC(+sbC)   (pairs dead now)
    fused_conv_kernel<0, 0><<<ab, 256, 0, stream>>>(sbB, rowptr, csr_src, dinv, W[2], B[2], nullptr, nullptr, sbA, n);
    fused_conv_kernel<1, 1><<<ab, 256, 0, stream>>>(sbA, rowptr, csr_src, dinv, W[3], B[3], bufB,    bufC,    sbC, n);
    // Res-block 3: bufC --(c4)--> sbA --(c5)--> bufB (final, no sb out)
    fused_conv_kernel<0, 0><<<ab, 256, 0, stream>>>(sbC, rowptr, csr_src, dinv, W[4], B[4], nullptr, nullptr, sbA, n);
    fused_conv_kernel<1, 1><<<ab, 256, 0, stream>>>(sbA, rowptr, csr_src, dinv, W[5], B[5], bufC,    bufB,    nullptr, n);

    pool_fc_kernel<<<gN, 128, 0, stream>>>(bufB, batch, flag, Wl, bl, out, n);
}

// Round 7
// 521.769 us; speedup vs baseline: 1.4341x; 1.4341x over previous
//
#include <hip/hip_runtime.h>
#include <hip/hip_bf16.h>
#include <cstdint>

#define DIM 32
#define OUTD 128
#define B_PART 256     // blocks in hist/partition passes
#define BSHIFT 9       // bucket = 512 nodes
#define SRCSHIFT 12    // source-sort granularity (4096 nodes per band)

// ---------------- bf16 helpers (RNE) ----------------
__device__ __forceinline__ unsigned short f32_to_bf16_rne(float f) {
    unsigned u = __float_as_uint(f);
    unsigned r = u + 0x7FFFu + ((u >> 16) & 1u);
    return (unsigned short)(r >> 16);
}
__device__ __forceinline__ float bf16_to_f32(unsigned short h) {
    return __uint_as_float(((unsigned)h) << 16);
}

// ---------------- index-load helper (int32 vs int64 inputs) ----------------
__device__ __forceinline__ int load_idx(const void* p, long long i, int is64) {
    if (is64) return (int)((const long long*)p)[i];
    return ((const int*)p)[i];
}

// Detect whether integer inputs are int64 (8B) or int32 (4B).
__global__ void detect_dtype_kernel(const void* __restrict__ edge, int* __restrict__ flag, int n_nodes) {
    __shared__ int cnt;
    if (threadIdx.x == 0) cnt = 0;
    __syncthreads();
    long long v = ((const long long*)edge)[threadIdx.x];
    int ok = (v >= 0 && v < (long long)n_nodes) ? 1 : 0;
    atomicAdd(&cnt, ok);
    __syncthreads();
    if (threadIdx.x == 0) *flag = (cnt > 128) ? 1 : 0;
}

// ---- pass 1: per-(bucket, block) histogram of destination buckets ----
__global__ __launch_bounds__(256) void hist_kernel(const void* __restrict__ edge,
                                                   const int* __restrict__ flag,
                                                   int* __restrict__ histT,
                                                   int eN, int NB, int chunk) {
    __shared__ int sh[256];
    int t = threadIdx.x, bid = blockIdx.x;
    sh[t] = 0;
    __syncthreads();
    int f = *flag;
    int s = bid * chunk, e = min(eN, s + chunk);
    for (int i = s + t; i < e; i += 256) {
        int c = load_idx(edge, (long long)eN + i, f);
        atomicAdd(&sh[c >> BSHIFT], 1);
    }
    __syncthreads();
    if (t < NB) histT[t * B_PART + bid] = sh[t];   // bucket-major layout
}

// ---- generic hierarchical exclusive scan over M ints (A: block sums) ----
__global__ __launch_bounds__(512) void scanA_kernel(const int* __restrict__ a,
                                                    int* __restrict__ sums, int M) {
    __shared__ int red[512];
    int i = blockIdx.x * 512 + threadIdx.x;
    int v = (i < M) ? a[i] : 0;
    red[threadIdx.x] = v;
    __syncthreads();
    for (int off = 256; off > 0; off >>= 1) {
        if (threadIdx.x < off) red[threadIdx.x] += red[threadIdx.x + off];
        __syncthreads();
    }
    if (threadIdx.x == 0) sums[blockIdx.x] = red[0];
}

// ---- B: exclusive scan of block sums (<=1024) ----
__global__ __launch_bounds__(1024) void scanB_kernel(int* __restrict__ sums, int nb) {
    __shared__ int part[1024];
    int t = threadIdx.x;
    int v = (t < nb) ? sums[t] : 0;
    part[t] = v;
    __syncthreads();
    for (int off = 1; off < 1024; off <<= 1) {
        int u = (t >= off) ? part[t - off] : 0;
        __syncthreads();
        part[t] += u;
        __syncthreads();
    }
    if (t < nb) sums[t] = part[t] - v;
}

// ---- C: apply (in-place exclusive scan) ----
__global__ __launch_bounds__(512) void scanC_kernel(int* __restrict__ a,
                                                    const int* __restrict__ sums, int M) {
    __shared__ int part[512];
    int t = threadIdx.x;
    int i = blockIdx.x * 512 + t;
    int v = (i < M) ? a[i] : 0;
    part[t] = v;
    __syncthreads();
    for (int off = 1; off < 512; off <<= 1) {
        int u = (t >= off) ? part[t - off] : 0;
        __syncthreads();
        part[t] += u;
        __syncthreads();
    }
    if (i < M) a[i] = part[t] - v + sums[blockIdx.x];
}

// ---- pass 2: partition edges into bucket runs; pack (r | local_c<<23) in 4B ----
__global__ __launch_bounds__(256) void partition_kernel(const void* __restrict__ edge,
                                                        const int* __restrict__ flag,
                                                        const int* __restrict__ offs,
                                                        unsigned int* __restrict__ pairs,
                                                        int eN, int NB, int chunk) {
    __shared__ int cur[256];
    int t = threadIdx.x, bid = blockIdx.x;
    if (t < NB) cur[t] = offs[t * B_PART + bid];
    __syncthreads();
    int f = *flag;
    int s = bid * chunk, e = min(eN, s + chunk);
    for (int i = s + t; i < e; i += 256) {
        int r = load_idx(edge, i, f);
        int c = load_idx(edge, (long long)eN + i, f);
        int slot = atomicAdd(&cur[c >> BSHIFT], 1);
        pairs[slot] = (unsigned)r | ((unsigned)(c & 511) << 23);
    }
}

// ---- pass 3: per-bucket CSR build via single-pass LDS counting sort ----
// Key = (local_node, src_band); lc-major/band-minor scan order makes each
// row's edge list band-sorted (coarse source order) => conv blocks sweep sb
// in near-lockstep => L2-resident hot window. 2 edge sweeps, NP-independent.
__global__ __launch_bounds__(256) void bucket_fill_kernel(const unsigned int* __restrict__ pairs,
                                                          const int* __restrict__ offs,
                                                          int* __restrict__ rowptr,
                                                          float* __restrict__ dinv,
                                                          int* __restrict__ csr_src,
                                                          int n, int eN, int NB, int NP) {
    extern __shared__ int cnt2[];          // 512 * NP
    __shared__ int psum[256];
    int t = threadIdx.x, b = blockIdx.x;
    int base = b << BSHIFT;
    int nLocal = min(512, n - base);
    int s = offs[b * B_PART];
    int e = (b + 1 < NB) ? offs[(b + 1) * B_PART] : eN;
    int M2 = 512 * NP;
    for (int i = t; i < M2; i += 256) cnt2[i] = 0;
    __syncthreads();
    // count (lc, band)
    for (int i = s + t; i < e; i += 256) {
        unsigned p = pairs[i];
        int lc = (int)(p >> 23);
        int r = (int)(p & 0x7FFFFFu);
        atomicAdd(&cnt2[lc * NP + (r >> SRCSHIFT)], 1);
    }
    __syncthreads();
    // exclusive scan of cnt2 (lc-major, band-minor)
    int chunk = (M2 + 255) / 256;
    int cs = t * chunk, ce = min(cs + chunk, M2);
    int sum = 0;
    for (int i = cs; i < ce; ++i) sum += cnt2[i];
    psum[t] = sum;
    __syncthreads();
    for (int off = 1; off < 256; off <<= 1) {
        int u = (t >= off) ? psum[t - off] : 0;
        __syncthreads();
        psum[t] += u;
        __syncthreads();
    }
    int run = psum[t] - sum;
    for (int i = cs; i < ce; ++i) {
        int c = cnt2[i];
        cnt2[i] = run;
        run += c;
    }
    __syncthreads();
    // rowptr + dinv
    for (int j = t; j < nLocal; j += 256) {
        int st = cnt2[j * NP];
        int en = (j < 511) ? cnt2[(j + 1) * NP] : (e - s);
        rowptr[base + j] = s + st;
        dinv[base + j] = rsqrtf((float)(en - st + 1));
    }
    if (b == NB - 1 && t == 0) rowptr[n] = eN;
    __syncthreads();
    // placement
    for (int i = s + t; i < e; i += 256) {
        unsigned p = pairs[i];
        int lc = (int)(p >> 23);
        int r = (int)(p & 0x7FFFFFu);
        int slot = atomicAdd(&cnt2[lc * NP + (r >> SRCSHIFT)], 1);
        csr_src[s + slot] = r;
    }
}

// prep: sb[i] = bf16(dinv[node] * x[i])
__global__ __launch_bounds__(256) void prescale_kernel(const float* __restrict__ x,
                                                       const float* __restrict__ dinv,
                                                       unsigned short* __restrict__ sb, int total) {
    int i = blockIdx.x * 256 + threadIdx.x;
    if (i >= total) return;
    sb[i] = f32_to_bf16_rne(dinv[i >> 5] * x[i]);
}

// Fused GCN conv on pre-scaled bf16 rows:
//   agg_k = dinv_c * ( sum_e sb[src_e][k] + sb[c][k] )        (sb = bf16(dinv*h))
//   o     = relu( agg @ W + b (+ res) )
//   WRITE_F32: store o to out (f32); sb_out (if non-null): bf16(dinv_c * o)
template <int HAS_RES, int WRITE_F32>
__global__ __launch_bounds__(256) void fused_conv_kernel(const unsigned short* __restrict__ sb,
                                                         const int* __restrict__ rowptr,
                                                         const int* __restrict__ src,
                                                         const float* __restrict__ dinv,
                                                         const float* __restrict__ W,
                                                         const float* __restrict__ bias,
                                                         const float* __restrict__ res,
                                                         float* __restrict__ out,
                                                         unsigned short* __restrict__ sb_out,
                                                         int n) {
    int t = threadIdx.x;
    int k = t & 31;
    float wr[32];
    #pragma unroll
    for (int j = 0; j < 32; ++j) wr[j] = W[j * 32 + k];
    float bk = bias[k];
    int g = blockIdx.x * 8 + (t >> 5);
    if (g >= n) return;
    float di = dinv[g];
    float acc = bf16_to_f32(sb[(size_t)g * 32 + k]);   // self term (pre-scaled)
    int s = rowptr[g], e = rowptr[g + 1];
    int p = s;
    for (; p + 7 < e; p += 8) {
        int sr0 = src[p];
        int sr1 = src[p + 1];
        int sr2 = src[p + 2];
        int sr3 = src[p + 3];
        int sr4 = src[p + 4];
        int sr5 = src[p + 5];
        int sr6 = src[p + 6];
        int sr7 = src[p + 7];
        float v0 = bf16_to_f32(sb[(size_t)sr0 * 32 + k]);
        float v1 = bf16_to_f32(sb[(size_t)sr1 * 32 + k]);
        float v2 = bf16_to_f32(sb[(size_t)sr2 * 32 + k]);
        float v3 = bf16_to_f32(sb[(size_t)sr3 * 32 + k]);
        float v4 = bf16_to_f32(sb[(size_t)sr4 * 32 + k]);
        float v5 = bf16_to_f32(sb[(size_t)sr5 * 32 + k]);
        float v6 = bf16_to_f32(sb[(size_t)sr6 * 32 + k]);
        float v7 = bf16_to_f32(sb[(size_t)sr7 * 32 + k]);
        acc += ((v0 + v1) + (v2 + v3)) + ((v4 + v5) + (v6 + v7));
    }
    for (; p < e; ++p) {
        int sr = src[p];
        acc += bf16_to_f32(sb[(size_t)sr * 32 + k]);
    }
    float agg = di * acc;
    float o = bk;
    #pragma unroll
    for (int j = 0; j < 32; ++j) {
        float aj = __shfl(agg, j, 32);
        o = fmaf(aj, wr[j], o);
    }
    if (HAS_RES) o += res[(size_t)g * 32 + k];
    o = fmaxf(o, 0.f);
    if (WRITE_F32) out[(size_t)g * 32 + k] = o;
    if (sb_out) sb_out[(size_t)g * 32 + k] = f32_to_bf16_rne(di * o);
}

// one block per graph: mean-pool (batch is sorted -> binary search range) + 32->128 FC
__global__ __launch_bounds__(128) void pool_fc_kernel(const float* __restrict__ h,
                                                      const void* __restrict__ batch,
                                                      const int* __restrict__ flag,
                                                      const float* __restrict__ Wl,
                                                      const float* __restrict__ bl,
                                                      float* __restrict__ out, int n) {
    __shared__ float red[4][32];
    __shared__ float sp[32];
    __shared__ int srange[2];
    int g = blockIdx.x;
    int t = threadIdx.x;
    int f = *flag;
    if (t < 2) {
        int target = g + t;
        int lo = 0, hi = n;
        while (lo < hi) {
            int mid = (lo + hi) >> 1;
            int v = load_idx(batch, mid, f);
            if (v < target) lo = mid + 1; else hi = mid;
        }
        srange[t] = lo;
    }
    __syncthreads();
    int s = srange[0], e = srange[1];
    int gi = t >> 5, k = t & 31;
    float acc = 0.f;
    for (int i = s + gi; i < e; i += 4) acc += h[(size_t)i * 32 + k];
    red[gi][k] = acc;
    __syncthreads();
    if (gi == 0) {
        float v = red[0][k] + red[1][k] + red[2][k] + red[3][k];
        sp[k] = v / fmaxf((float)(e - s), 1.0f);
    }
    __syncthreads();
    float val = bl[t];
    #pragma unroll
    for (int j = 0; j < 32; ++j) val = fmaf(sp[j], Wl[j * 128 + t], val);
    out[(size_t)g * 128 + t] = val;
}

extern "C" void kernel_launch(void* const* d_in, const int* in_sizes, int n_in,
                              void* d_out, int out_size, void* d_ws, size_t ws_size,
                              hipStream_t stream) {
    const float* x = (const float*)d_in[0];
    const void* edge = d_in[1];
    const void* batch = d_in[2];
    const float* W[6] = {(const float*)d_in[3], (const float*)d_in[5],
                         (const float*)d_in[7], (const float*)d_in[9],
                         (const float*)d_in[11], (const float*)d_in[13]};
    const float* B[6] = {(const float*)d_in[4], (const float*)d_in[6],
                         (const float*)d_in[8], (const float*)d_in[10],
                         (const float*)d_in[12], (const float*)d_in[14]};
    const float* Wl = (const float*)d_in[15];
    const float* bl = (const float*)d_in[16];
    float* out = (float*)d_out;

    int n = in_sizes[0] / DIM;      // 100000 nodes
    int eN = in_sizes[1] / 2;       // 3200000 edges
    int gN = out_size / OUTD;       // 8192 graphs

    int NB = (n + 511) >> BSHIFT;   // 196 buckets (<=256 for n<=131072)
    int M = NB * B_PART;            // hist matrix size
    int chunk = (eN + B_PART - 1) / B_PART;
    int nbA = (M + 511) / 512;
    int NP = ((n - 1) >> SRCSHIFT) + 1;   // source bands (25 for n=100k)
    size_t fillLds = (size_t)512 * NP * 4;

    char* ws = (char*)d_ws;
    size_t off = 0;
    auto alloc = [&](size_t bytes) {
        void* p = ws + off;
        off += (bytes + 255) & ~(size_t)255;
        return p;
    };
    int* flag      = (int*)alloc(4);
    int* offs      = (int*)alloc((size_t)B_PART * 256 * 4);   // hist/offsets (bucket-major)
    int* sumsA     = (int*)alloc(1024 * 4);
    int* rowptr    = (int*)alloc((size_t)(n + 1) * 4);
    float* dinv    = (float*)alloc((size_t)n * 4);
    int* csr_src   = (int*)alloc((size_t)eN * 4);
    float* bufB    = (float*)alloc((size_t)n * DIM * 4);
    unsigned short* sbX = (unsigned short*)alloc((size_t)n * DIM * 2);
    unsigned short* sbA = (unsigned short*)alloc((size_t)n * DIM * 2);
    unsigned short* sbB = (unsigned short*)alloc((size_t)n * DIM * 2);
    unsigned short* sbC = (unsigned short*)alloc((size_t)n * DIM * 2);
    size_t pairsB  = (size_t)eN * 4;
    size_t bufCB   = (size_t)n * DIM * 4;
    void* shared0  = alloc(pairsB > bufCB ? pairsB : bufCB);  // pairs, later bufC
    unsigned int* pairs = (unsigned int*)shared0;
    float* bufC    = (float*)shared0;

    detect_dtype_kernel<<<1, 256, 0, stream>>>(edge, flag, n);
    hist_kernel<<<B_PART, 256, 0, stream>>>(edge, flag, offs, eN, NB, chunk);
    scanA_kernel<<<nbA, 512, 0, stream>>>(offs, sumsA, M);
    scanB_kernel<<<1, 1024, 0, stream>>>(sumsA, nbA);
    scanC_kernel<<<nbA, 512, 0, stream>>>(offs, sumsA, M);
    partition_kernel<<<B_PART, 256, 0, stream>>>(edge, flag, offs, pairs, eN, NB, chunk);
    bucket_fill_kernel<<<NB, 256, fillLds, stream>>>(pairs, offs, rowptr, dinv, csr_src, n, eN, NB, NP);

    int total = n * DIM;
    prescale_kernel<<<(total + 255) / 256, 256, 0, stream>>>(x, dinv, sbX, total);

    int ab = (n + 7) / 8;

    // Res-block 1: x --(c0)--> sbA --(c1)--> bufB(+sbB)
    fused_conv_kernel<0, 0><<<ab, 256, 0, stream>>>(sbX, rowptr, csr_src, dinv, W[0], B[0], nullptr, nullptr, sbA, n);
    fused_conv_kernel<1, 1><<<ab, 256, 0, stream>>>(sbA, rowptr, csr_src, dinv, W[1], B[1], x,       bufB,    sbB, n);
    // Res-block 2: bufB --(c2)--> sbA --(c3)--> bufC(+sbC)   (pairs dead now)
    fused_conv_kernel<0, 0><<<ab, 256, 0, stream>>>(sbB, rowptr, csr_src, dinv, W[2], B[2], nullptr, nullptr, sbA, n);
    fused_conv_kernel<1, 1><<<ab, 256, 0, stream>>>(sbA, rowptr, csr_src, dinv, W[3], B[3], bufB,    bufC,    sbC, n);
    // Res-block 3: bufC --(c4)--> sbA --(c5)--> bufB (final, no sb out)
    fused_conv_kernel<0, 0><<<ab, 256, 0, stream>>>(sbC, rowptr, csr_src, dinv, W[4], B[4], nullptr, nullptr, sbA, n);
    fused_conv_kernel<1, 1><<<ab, 256, 0, stream>>>(sbA, rowptr, csr_src, dinv, W[5], B[5], bufC,    bufB,    nullptr, n);

    pool_fc_kernel<<<gN, 128, 0, stream>>>(bufB, batch, flag, Wl, bl, out, n);
}